// Round 3
// baseline (199.444 us; speedup 1.0000x reference)
//
#include <hip/hip_runtime.h>
#include <math.h>

#define NS    512
#define NOBJ  16
#define MPTS  8192
#define HH    128
#define WW    128
#define HW    (HH * WW)

// ---- pixel kernel geometry: lean + high occupancy ----
#define PXB   256                   // threads per pixel block (4 waves)
#define QS    4                     // pixel blocks per sample
#define PXW   (HW / QS / 4)         // px per wave = 1024
#define PSTG  256                   // px per stage per wave (f4 per lane)
#define PNST  (PXW / PSTG)          // 4 stages, depth-2 pipeline

// ---- final kernel geometry ----
#define FXB   256
#define M_IT  (MPTS / 4 / FXB)      // 8 mesh quad-groups per thread

typedef float f4 __attribute__((ext_vector_type(4)));
typedef int   i4 __attribute__((ext_vector_type(4)));

__device__ __forceinline__ float frcp(float x)  { return __builtin_amdgcn_rcpf(x); }
__device__ __forceinline__ float fsqrt(float x) { return __builtin_amdgcn_sqrtf(x); }
__device__ __forceinline__ float rfl(float x) {
    return __int_as_float(__builtin_amdgcn_readfirstlane(__float_as_int(x)));
}

// R3 change: drop the non-temporal hint. Theory — reads, not writes, are
// capped (~2.4 TB/s) for EVERY read path in this window, including the
// runtime's own copyBuffer (3.3 TB/s R+W vs fill's 6.7 TB/s pure-write).
// All prior variants (pattern, phase, occupancy) shared one constant: NT
// loads, which set no-allocate policy and skip the 256-MB L3. The harness's
// restore copy leaves coord (100 MB) + mask (34 MB) L3-resident right
// before our kernel runs — plain cached loads should turn the pixel stream
// into Infinity-Cache hits. Single-variable A/B vs R2.
__device__ __forceinline__ f4 ld_f4(const f4* p) { return *p; }
__device__ __forceinline__ i4 ld_i4(const i4* p) { return *p; }

__device__ __forceinline__ void fuse_proj(const float* __restrict__ cam_K,
                                          const float* __restrict__ R,
                                          const float* __restrict__ t, int n,
                                          float A[9], float b[3]) {
    float K[9], Rr[9], tt[3];
#pragma unroll
    for (int i = 0; i < 9; ++i) { K[i] = cam_K[n * 9 + i]; Rr[i] = R[n * 9 + i]; }
#pragma unroll
    for (int i = 0; i < 3; ++i) tt[i] = t[n * 3 + i];
#pragma unroll
    for (int r = 0; r < 3; ++r) {
#pragma unroll
        for (int c = 0; c < 3; ++c)
            A[r * 3 + c] = rfl(K[r * 3 + 0] * Rr[0 * 3 + c]
                             + K[r * 3 + 1] * Rr[1 * 3 + c]
                             + K[r * 3 + 2] * Rr[2 * 3 + c]);
        b[r] = rfl(K[r * 3 + 0] * tt[0] + K[r * 3 + 1] * tt[1] + K[r * 3 + 2] * tt[2]);
    }
}

__global__ __attribute__((amdgpu_flat_work_group_size(PXB, PXB),
                          amdgpu_waves_per_eu(8, 8)))
void pixel_kernel(
    const float* __restrict__ cam_K,
    const float* __restrict__ gt_R,
    const float* __restrict__ gt_t,
    const float* __restrict__ pr_R,
    const float* __restrict__ pr_t,
    const float* __restrict__ coord,      // [N,3,H,W]
    const int*   __restrict__ mask,       // [N,1,H,W]
    float*       __restrict__ ws)         // [NS*QS*2] partials
{
    const int bid  = blockIdx.x;
    const int n    = bid >> 2;
    const int q    = bid & (QS - 1);
    const int tid  = threadIdx.x;
    const int w    = tid >> 6;
    const int lane = tid & 63;

    float Ap[9], Ag[9], bp[3], bg[3];
    fuse_proj(cam_K, pr_R, pr_t, n, Ap, bp);
    fuse_proj(cam_K, gt_R, gt_t, n, Ag, bg);

    const int base = q * (HW / QS) + w * PXW + 4 * lane;
    const float* cx = coord + (size_t)n * 3 * HW + base;
    const float* cy = cx + HW;
    const float* cz = cx + 2 * HW;
    const int*   mk = mask + (size_t)n * HW + base;

    f4 X[2], Y[2], Z[2];
    i4 Mq[2];

#define PLOAD(s, b)                                                          \
    {                                                                        \
        const int p = (s) * PSTG;                                            \
        X[b]  = ld_f4((const f4*)(cx + p));                                  \
        Y[b]  = ld_f4((const f4*)(cy + p));                                  \
        Z[b]  = ld_f4((const f4*)(cz + p));                                  \
        Mq[b] = ld_i4((const i4*)(mk + p));                                  \
    }

    PLOAD(0, 0)
    PLOAD(1, 1)

    float s_pv = 0.0f, s_m = 0.0f;
#pragma unroll
    for (int s = 0; s < PNST; ++s) {
        const int b = s & 1;
        const float xs[4] = {X[b].x, X[b].y, X[b].z, X[b].w};
        const float ys[4] = {Y[b].x, Y[b].y, Y[b].z, Y[b].w};
        const float zs[4] = {Z[b].x, Z[b].y, Z[b].z, Z[b].w};
        const int   ms[4] = {Mq[b].x, Mq[b].y, Mq[b].z, Mq[b].w};
#pragma unroll
        for (int j = 0; j < 4; ++j) {
            const float x = xs[j], y = ys[j], z = zs[j];
            const float hpx = fmaf(Ap[0], x, fmaf(Ap[1], y, fmaf(Ap[2], z, bp[0])));
            const float hpy = fmaf(Ap[3], x, fmaf(Ap[4], y, fmaf(Ap[5], z, bp[1])));
            const float hpz = fmaf(Ap[6], x, fmaf(Ap[7], y, fmaf(Ap[8], z, bp[2])));
            const float hgx = fmaf(Ag[0], x, fmaf(Ag[1], y, fmaf(Ag[2], z, bg[0])));
            const float hgy = fmaf(Ag[3], x, fmaf(Ag[4], y, fmaf(Ag[5], z, bg[1])));
            const float hgz = fmaf(Ag[6], x, fmaf(Ag[7], y, fmaf(Ag[8], z, bg[2])));
            const float iwp = frcp(hpz), iwg = frcp(hgz);
            const float du = fmaf(hpx, iwp, -hgx * iwg);
            const float dv = fmaf(hpy, iwp, -hgy * iwg);
            const float d  = fsqrt(fmaf(du, du, dv * dv));
            const float fm = (ms[j] != 0) ? 1.0f : 0.0f;
            s_pv += d * fm;
            s_m  += fm;
        }
        if (s + 2 < PNST) PLOAD(s + 2, b)
    }

    // 2-value reduction over 4 waves
#pragma unroll
    for (int off = 32; off > 0; off >>= 1) {
        s_pv += __shfl_down(s_pv, off, 64);
        s_m  += __shfl_down(s_m,  off, 64);
    }
    __shared__ float red[2][PXB / 64];
    if (lane == 0) { red[0][w] = s_pv; red[1][w] = s_m; }
    __syncthreads();
    if (tid == 0) {
        float a = 0.0f, m = 0.0f;
#pragma unroll
        for (int wv = 0; wv < PXB / 64; ++wv) { a += red[0][wv]; m += red[1][wv]; }
        ws[bid * 2 + 0] = a;
        ws[bid * 2 + 1] = m;
    }
}

// mesh phase + scalar outputs + partial combine (L2-hot, ~5 us)
__global__ __launch_bounds__(FXB)
void final_kernel(
    const int*   __restrict__ obj_id,
    const float* __restrict__ cam_K,
    const float* __restrict__ gt_R,
    const float* __restrict__ gt_t,
    const float* __restrict__ pr_R,
    const float* __restrict__ pr_t,
    const float* __restrict__ mesh,       // [NOBJ,M,3]
    const float* __restrict__ diam,
    const float* __restrict__ ws,         // [NS*QS*2]
    float*       __restrict__ out)        // [5*N]
{
    const int n    = blockIdx.x;
    const int tid  = threadIdx.x;
    const int w    = tid >> 6;
    const int lane = tid & 63;

    float Ap[9], Ag[9], bp[3], bg[3], dR[9], dt[3];
    fuse_proj(cam_K, pr_R, pr_t, n, Ap, bp);
    fuse_proj(cam_K, gt_R, gt_t, n, Ag, bg);
#pragma unroll
    for (int i = 0; i < 9; ++i) dR[i] = rfl(pr_R[n * 9 + i] - gt_R[n * 9 + i]);
#pragma unroll
    for (int i = 0; i < 3; ++i) dt[i] = rfl(pr_t[n * 3 + i] - gt_t[n * 3 + i]);
    const int obj = __builtin_amdgcn_readfirstlane(obj_id[n]);

    const f4* mp4 = (const f4*)(mesh + (size_t)obj * MPTS * 3);

    float s_ad = 0.0f, s_pj = 0.0f;
#pragma unroll
    for (int it = 0; it < M_IT; ++it) {
        const int k = it * FXB + tid;
        const f4 f0 = mp4[k * 3 + 0];
        const f4 f1 = mp4[k * 3 + 1];
        const f4 f2 = mp4[k * 3 + 2];
        const float px[4] = {f0.x, f0.w, f1.z, f2.y};
        const float py[4] = {f0.y, f1.x, f1.w, f2.z};
        const float pz[4] = {f0.z, f1.y, f2.x, f2.w};
#pragma unroll
        for (int j = 0; j < 4; ++j) {
            const float x = px[j], y = py[j], z = pz[j];
            const float dx = fmaf(dR[0], x, fmaf(dR[1], y, fmaf(dR[2], z, dt[0])));
            const float dy = fmaf(dR[3], x, fmaf(dR[4], y, fmaf(dR[5], z, dt[1])));
            const float dz = fmaf(dR[6], x, fmaf(dR[7], y, fmaf(dR[8], z, dt[2])));
            s_ad += fsqrt(fmaf(dx, dx, fmaf(dy, dy, dz * dz)));
            const float hpx = fmaf(Ap[0], x, fmaf(Ap[1], y, fmaf(Ap[2], z, bp[0])));
            const float hpy = fmaf(Ap[3], x, fmaf(Ap[4], y, fmaf(Ap[5], z, bp[1])));
            const float hpz = fmaf(Ap[6], x, fmaf(Ap[7], y, fmaf(Ap[8], z, bp[2])));
            const float hgx = fmaf(Ag[0], x, fmaf(Ag[1], y, fmaf(Ag[2], z, bg[0])));
            const float hgy = fmaf(Ag[3], x, fmaf(Ag[4], y, fmaf(Ag[5], z, bg[1])));
            const float hgz = fmaf(Ag[6], x, fmaf(Ag[7], y, fmaf(Ag[8], z, bg[2])));
            const float iwp = frcp(hpz), iwg = frcp(hgz);
            const float du = fmaf(hpx, iwp, -hgx * iwg);
            const float dv = fmaf(hpy, iwp, -hgy * iwg);
            s_pj += fsqrt(fmaf(du, du, dv * dv));
        }
    }

#pragma unroll
    for (int off = 32; off > 0; off >>= 1) {
        s_ad += __shfl_down(s_ad, off, 64);
        s_pj += __shfl_down(s_pj, off, 64);
    }
    __shared__ float red[2][FXB / 64];
    if (lane == 0) { red[0][w] = s_ad; red[1][w] = s_pj; }
    __syncthreads();

    if (tid == 0) {
        float ad = 0.0f, pj = 0.0f;
#pragma unroll
        for (int wv = 0; wv < FXB / 64; ++wv) { ad += red[0][wv]; pj += red[1][wv]; }

        float pv_d = 0.0f, pv_m = 0.0f;
#pragma unroll
        for (int qq = 0; qq < QS; ++qq) {
            pv_d += ws[(n * QS + qq) * 2 + 0];
            pv_m += ws[(n * QS + qq) * 2 + 1];
        }

        float Rg9[9], Rp9[9];
#pragma unroll
        for (int i = 0; i < 9; ++i) { Rg9[i] = gt_R[n * 9 + i]; Rp9[i] = pr_R[n * 9 + i]; }
        float trace = 0.0f;
#pragma unroll
        for (int i = 0; i < 9; ++i) trace += Rp9[i] * Rg9[i];
        trace = fminf(fmaxf(trace, -1.0f), 3.0f);
        const float te = sqrtf(dt[0] * dt[0] + dt[1] * dt[1] + dt[2] * dt[2]) * 100.0f;

        out[0 * NS + n] = acosf((trace - 1.0f) * 0.5f) * (180.0f / 3.14159265358979323846f);
        out[1 * NS + n] = te;
        out[2 * NS + n] = ad * (1.0f / MPTS) / diam[obj];
        out[3 * NS + n] = pj * (1.0f / MPTS);
        out[4 * NS + n] = pv_d / fmaxf(pv_m, 1.0f);
    }
}

extern "C" void kernel_launch(void* const* d_in, const int* in_sizes, int n_in,
                              void* d_out, int out_size, void* d_ws, size_t ws_size,
                              hipStream_t stream) {
    const int*   obj_id = (const int*)  d_in[0];
    const float* cam_K  = (const float*)d_in[1];
    const float* gt_R   = (const float*)d_in[2];
    const float* gt_t   = (const float*)d_in[3];
    const float* pr_R   = (const float*)d_in[4];
    const float* pr_t   = (const float*)d_in[5];
    const float* coord  = (const float*)d_in[6];
    const int*   mask   = (const int*)  d_in[7];
    const float* mesh   = (const float*)d_in[8];
    const float* diam   = (const float*)d_in[9];
    float* out = (float*)d_out;
    float* ws  = (float*)d_ws;

    pixel_kernel<<<NS * QS, PXB, 0, stream>>>(cam_K, gt_R, gt_t, pr_R, pr_t,
                                              coord, mask, ws);
    final_kernel<<<NS, FXB, 0, stream>>>(obj_id, cam_K, gt_R, gt_t, pr_R, pr_t,
                                         mesh, diam, ws, out);
}

// Round 4
// 182.966 us; speedup vs baseline: 1.0901x; 1.0901x over previous
//
#include <hip/hip_runtime.h>
#include <math.h>

#define NS    512
#define NOBJ  16
#define MPTS  8192
#define HH    128
#define WW    128
#define HW    (HH * WW)
#define BLOCK 512
#define NWAVE (BLOCK / 64)
#define WSPAN (HW / NWAVE)          // 2048 contiguous px per wave
#define GRP   256                   // px per dwordx4 wave-instruction
#define STG   2                     // insts per array per stage (2-KB runs)
#define NSTG  (WSPAN / (GRP * STG)) // 4 stages per wave
#define M_IT  (MPTS / 4 / BLOCK)    // 4 mesh groups per thread

typedef float f4 __attribute__((ext_vector_type(4)));
typedef int   i4 __attribute__((ext_vector_type(4)));

__device__ __forceinline__ float frcp(float x)  { return __builtin_amdgcn_rcpf(x); }
__device__ __forceinline__ float fsqrt(float x) { return __builtin_amdgcn_sqrtf(x); }
__device__ __forceinline__ float rfl(float x) {
    return __int_as_float(__builtin_amdgcn_readfirstlane(__float_as_int(x)));
}
__device__ __forceinline__ void sched_fence() {
#if __has_builtin(__builtin_amdgcn_sched_barrier)
    __builtin_amdgcn_sched_barrier(0);
#endif
}

// R4: streaming-bypass loads. R3 proved cache policy is the ONLY lever that
// moves this kernel (cached = 2.4 TB/s, nt = 3.46 TB/s). The builtin NT sets
// only the nt bit; sc0+sc1 additionally bypass L1/L2 allocation (gfx940+
// cpol). Theory: the 3.46 TB/s read cap is L2 tag/allocate overhead on a
// pure-miss stream; full bypass should push toward the write-side 6.9 TB/s.
// Hand-rolled asm loads need hand-rolled waits: s_waitcnt vmcnt(N) +
// sched_barrier(0) before each stage's consumption (guide rule #18).
__device__ __forceinline__ f4 ld_stream_f4(const f4* p) {
    f4 v;
    asm volatile("global_load_dwordx4 %0, %1, off sc0 sc1 nt"
                 : "=v"(v) : "v"(p) : "memory");
    return v;
}
__device__ __forceinline__ i4 ld_stream_i4(const i4* p) {
    i4 v;
    asm volatile("global_load_dwordx4 %0, %1, off sc0 sc1 nt"
                 : "=v"(v) : "v"(p) : "memory");
    return v;
}
#define WAIT_VM_8() { asm volatile("s_waitcnt vmcnt(8)" ::: "memory"); sched_fence(); }
#define WAIT_VM_0() { asm volatile("s_waitcnt vmcnt(0)" ::: "memory"); sched_fence(); }

__device__ __forceinline__ void fuse_proj(const float* __restrict__ cam_K,
                                          const float* __restrict__ R,
                                          const float* __restrict__ t, int n,
                                          float A[9], float b[3]) {
    float K[9], Rr[9], tt[3];
#pragma unroll
    for (int i = 0; i < 9; ++i) { K[i] = cam_K[n * 9 + i]; Rr[i] = R[n * 9 + i]; }
#pragma unroll
    for (int i = 0; i < 3; ++i) tt[i] = t[n * 3 + i];
#pragma unroll
    for (int r = 0; r < 3; ++r) {
#pragma unroll
        for (int c = 0; c < 3; ++c)
            A[r * 3 + c] = rfl(K[r * 3 + 0] * Rr[0 * 3 + c]
                             + K[r * 3 + 1] * Rr[1 * 3 + c]
                             + K[r * 3 + 2] * Rr[2 * 3 + c]);
        b[r] = rfl(K[r * 3 + 0] * tt[0] + K[r * 3 + 1] * tt[1] + K[r * 3 + 2] * tt[2]);
    }
}

__global__ __attribute__((amdgpu_flat_work_group_size(BLOCK, BLOCK),
                          amdgpu_waves_per_eu(4, 4)))
void score_kernel(
    const int*   __restrict__ obj_id,
    const float* __restrict__ cam_K,
    const float* __restrict__ gt_R,
    const float* __restrict__ gt_t,
    const float* __restrict__ pr_R,
    const float* __restrict__ pr_t,
    const float* __restrict__ coord,      // [N,3,H,W]
    const int*   __restrict__ mask,       // [N,1,H,W]
    const float* __restrict__ mesh,       // [NOBJ,M,3]
    const float* __restrict__ diam,
    float*       __restrict__ out)        // [5*N]
{
    const int n    = blockIdx.x;
    const int tid  = threadIdx.x;
    const int w    = tid >> 6;
    const int lane = tid & 63;

    // ---- constants -> SGPR ----
    float Ap[9], Ag[9], bp[3], bg[3], dR[9], dt[3];
    fuse_proj(cam_K, pr_R, pr_t, n, Ap, bp);
    fuse_proj(cam_K, gt_R, gt_t, n, Ag, bg);
#pragma unroll
    for (int i = 0; i < 9; ++i) dR[i] = rfl(pr_R[n * 9 + i] - gt_R[n * 9 + i]);
#pragma unroll
    for (int i = 0; i < 3; ++i) dt[i] = rfl(pr_t[n * 3 + i] - gt_t[n * 3 + i]);
    const int obj = __builtin_amdgcn_readfirstlane(obj_id[n]);

    const float* cx = coord + (size_t)n * 3 * HW;
    const float* cy = cx + HW;
    const float* cz = cx + 2 * HW;
    const int*   mk = mask + (size_t)n * HW;
    const int wbase = w * WSPAN + 4 * lane;   // wave-sequential base

    // ---- pixel phase: depth-2 slot rotation over 4 stages ----
    f4 X[2][STG], Y[2][STG], Z[2][STG];
    i4 Mq[2][STG];

#define LOAD_STAGE(s, b)                                                     \
    {                                                                        \
        _Pragma("unroll")                                                    \
        for (int g = 0; g < STG; ++g) {                                      \
            const int p = wbase + (s) * (STG * GRP) + g * GRP;               \
            X[b][g]  = ld_stream_f4((const f4*)(cx + p));                    \
            Y[b][g]  = ld_stream_f4((const f4*)(cy + p));                    \
            Z[b][g]  = ld_stream_f4((const f4*)(cz + p));                    \
            Mq[b][g] = ld_stream_i4((const i4*)(mk + p));                    \
        }                                                                    \
    }

    LOAD_STAGE(0, 0)
    LOAD_STAGE(1, 1)

    float s_pv = 0.0f, s_m = 0.0f;
#pragma unroll
    for (int s = 0; s < NSTG; ++s) {
        const int b = s & 1;
        // stage s's 8 loads are the oldest in flight; 16 outstanding while
        // pipeline is full -> vmcnt(8); final stage has only its own 8 -> 0.
        if (s < NSTG - 1) { WAIT_VM_8() } else { WAIT_VM_0() }
#pragma unroll
        for (int g = 0; g < STG; ++g) {
            const float xs[4] = {X[b][g].x, X[b][g].y, X[b][g].z, X[b][g].w};
            const float ys[4] = {Y[b][g].x, Y[b][g].y, Y[b][g].z, Y[b][g].w};
            const float zs[4] = {Z[b][g].x, Z[b][g].y, Z[b][g].z, Z[b][g].w};
            const int   ms[4] = {Mq[b][g].x, Mq[b][g].y, Mq[b][g].z, Mq[b][g].w};
#pragma unroll
            for (int j = 0; j < 4; ++j) {
                const float x = xs[j], y = ys[j], z = zs[j];
                const float hpx = fmaf(Ap[0], x, fmaf(Ap[1], y, fmaf(Ap[2], z, bp[0])));
                const float hpy = fmaf(Ap[3], x, fmaf(Ap[4], y, fmaf(Ap[5], z, bp[1])));
                const float hpz = fmaf(Ap[6], x, fmaf(Ap[7], y, fmaf(Ap[8], z, bp[2])));
                const float hgx = fmaf(Ag[0], x, fmaf(Ag[1], y, fmaf(Ag[2], z, bg[0])));
                const float hgy = fmaf(Ag[3], x, fmaf(Ag[4], y, fmaf(Ag[5], z, bg[1])));
                const float hgz = fmaf(Ag[6], x, fmaf(Ag[7], y, fmaf(Ag[8], z, bg[2])));
                const float iwp = frcp(hpz), iwg = frcp(hgz);
                const float du = fmaf(hpx, iwp, -hgx * iwg);
                const float dv = fmaf(hpy, iwp, -hgy * iwg);
                const float d  = fsqrt(fmaf(du, du, dv * dv));
                const float fm = (ms[j] != 0) ? 1.0f : 0.0f;
                s_pv += d * fm;
                s_m  += fm;
            }
        }
        if (s + 2 < NSTG) {
            LOAD_STAGE(s + 2, b)      // refill freed slot; stream stays sequential
        }
    }

    // ---- mesh phase: batch issue, consume (L2/L3-warm) ----
    const f4* mp4 = (const f4*)(mesh + (size_t)obj * MPTS * 3);
    f4 MF[M_IT][3];
#pragma unroll
    for (int it = 0; it < M_IT; ++it) {
        const int k = it * BLOCK + tid;
        MF[it][0] = mp4[k * 3 + 0];
        MF[it][1] = mp4[k * 3 + 1];
        MF[it][2] = mp4[k * 3 + 2];
    }
    sched_fence();

    float s_ad = 0.0f, s_pj = 0.0f;
#pragma unroll
    for (int it = 0; it < M_IT; ++it) {
        const f4 f0 = MF[it][0], f1 = MF[it][1], f2 = MF[it][2];
        const float px[4] = {f0.x, f0.w, f1.z, f2.y};
        const float py[4] = {f0.y, f1.x, f1.w, f2.z};
        const float pz[4] = {f0.z, f1.y, f2.x, f2.w};
#pragma unroll
        for (int j = 0; j < 4; ++j) {
            const float x = px[j], y = py[j], z = pz[j];
            const float dx = fmaf(dR[0], x, fmaf(dR[1], y, fmaf(dR[2], z, dt[0])));
            const float dy = fmaf(dR[3], x, fmaf(dR[4], y, fmaf(dR[5], z, dt[1])));
            const float dz = fmaf(dR[6], x, fmaf(dR[7], y, fmaf(dR[8], z, dt[2])));
            s_ad += fsqrt(fmaf(dx, dx, fmaf(dy, dy, dz * dz)));
            const float hpx = fmaf(Ap[0], x, fmaf(Ap[1], y, fmaf(Ap[2], z, bp[0])));
            const float hpy = fmaf(Ap[3], x, fmaf(Ap[4], y, fmaf(Ap[5], z, bp[1])));
            const float hpz = fmaf(Ap[6], x, fmaf(Ap[7], y, fmaf(Ap[8], z, bp[2])));
            const float hgx = fmaf(Ag[0], x, fmaf(Ag[1], y, fmaf(Ag[2], z, bg[0])));
            const float hgy = fmaf(Ag[3], x, fmaf(Ag[4], y, fmaf(Ag[5], z, bg[1])));
            const float hgz = fmaf(Ag[6], x, fmaf(Ag[7], y, fmaf(Ag[8], z, bg[2])));
            const float iwp = frcp(hpz), iwg = frcp(hgz);
            const float du = fmaf(hpx, iwp, -hgx * iwg);
            const float dv = fmaf(hpy, iwp, -hgy * iwg);
            s_pj += fsqrt(fmaf(du, du, dv * dv));
        }
    }

    // ---- block reduction ----
    float vals[4] = {s_ad, s_pj, s_pv, s_m};
#pragma unroll
    for (int k = 0; k < 4; ++k)
#pragma unroll
        for (int off = 32; off > 0; off >>= 1)
            vals[k] += __shfl_down(vals[k], off, 64);

    __shared__ float red[4][NWAVE];
    if (lane == 0) {
#pragma unroll
        for (int k = 0; k < 4; ++k) red[k][w] = vals[k];
    }
    __syncthreads();

    if (tid == 0) {
        float tot[4];
#pragma unroll
        for (int k = 0; k < 4; ++k) {
            float s = 0.0f;
#pragma unroll
            for (int wv = 0; wv < NWAVE; ++wv) s += red[k][wv];
            tot[k] = s;
        }
        float Rg9[9], Rp9[9];
#pragma unroll
        for (int i = 0; i < 9; ++i) { Rg9[i] = gt_R[n * 9 + i]; Rp9[i] = pr_R[n * 9 + i]; }
        float trace = 0.0f;
#pragma unroll
        for (int i = 0; i < 9; ++i) trace += Rp9[i] * Rg9[i];
        trace = fminf(fmaxf(trace, -1.0f), 3.0f);
        const float te = sqrtf(dt[0] * dt[0] + dt[1] * dt[1] + dt[2] * dt[2]) * 100.0f;

        out[0 * NS + n] = acosf((trace - 1.0f) * 0.5f) * (180.0f / 3.14159265358979323846f);
        out[1 * NS + n] = te;
        out[2 * NS + n] = tot[0] * (1.0f / MPTS) / diam[obj];
        out[3 * NS + n] = tot[1] * (1.0f / MPTS);
        out[4 * NS + n] = tot[2] / fmaxf(tot[3], 1.0f);
    }
}

extern "C" void kernel_launch(void* const* d_in, const int* in_sizes, int n_in,
                              void* d_out, int out_size, void* d_ws, size_t ws_size,
                              hipStream_t stream) {
    const int*   obj_id = (const int*)  d_in[0];
    const float* cam_K  = (const float*)d_in[1];
    const float* gt_R   = (const float*)d_in[2];
    const float* gt_t   = (const float*)d_in[3];
    const float* pr_R   = (const float*)d_in[4];
    const float* pr_t   = (const float*)d_in[5];
    const float* coord  = (const float*)d_in[6];
    const int*   mask   = (const int*)  d_in[7];
    const float* mesh   = (const float*)d_in[8];
    const float* diam   = (const float*)d_in[9];
    float* out = (float*)d_out;

    score_kernel<<<NS, BLOCK, 0, stream>>>(obj_id, cam_K, gt_R, gt_t, pr_R, pr_t,
                                           coord, mask, mesh, diam, out);
}